// Round 12
// baseline (241.440 us; speedup 1.0000x reference)
//
#include <hip/hip_runtime.h>
#include <hip/hip_bf16.h>

#define NN 268
#define NE 8192
#define KP 288   // padded K (268 -> 288), shared by gemm1 / dense L / classifier

typedef short short8 __attribute__((ext_vector_type(8)));   // 8 bf16 = 4 VGPR
typedef short short4v __attribute__((ext_vector_type(4)));  // 4 bf16 = 8B
typedef float f32x4 __attribute__((ext_vector_type(4)));

__device__ __forceinline__ short f2bf(float f) {
  __hip_bfloat16 h = __float2bfloat16(f);
  return *reinterpret_cast<short*>(&h);
}

// ---------------------------------------------------------------------------
// Workspace offsets (bytes). Peak 56,163,328.
//   OFF_DEGI   degI   u32 [128][272]             139,264  (dead after dinv calc)
//   OFF_Y2T    Y2t    bf16[128][64][288]       4,718,592  (dead after dgemmA)
//     OFF_YB2T Yb2t   bf16[128][32][288]       2,359,296  (overlays Y2t head)
//     OFF_U2T  U2t    bf16[128][32][288]       2,359,296  (overlays Y2t tail)
//   OFF_UT     Ut     bf16[128][64][288]       4,718,592  (dead after dgemmB)
//     OFF_H2TB H2Tb   bf16[4096][288]          2,359,296  (overlays Ut head)
//   OFF_WBT    WbT    bf16[192][288]             110,592
//   OFF_WC1BT  Wc1bT  bf16[112][288]              64,512
//   OFF_LB     Lb     bf16[128][272][288]     20,054,016
//   OFF_Y      Y      f32 [128][268][192]     26,345,472
//   OFF_W4BT   W4bT   bf16[96][64]                12,288
//     dinv f32[128][272] (139 KB) overlays Y head — dead before gemm1 writes Y
//     Y cols per graph: 0-64 Y0 (later Yb0|Yb1), 64-128 Y1 (dead after dgemmA),
//                       128-192 Y2 (later cols 160-192 = Yb2)
// ---------------------------------------------------------------------------
#define OFF_DEGI  0
#define OFF_Y2T   139264
#define OFF_YB2T  139264
#define OFF_U2T   2498560
#define OFF_UT    4857856
#define OFF_H2TB  4857856
#define OFF_WBT   9576448
#define OFF_WC1BT 9687040
#define OFF_LB    9751552
#define OFF_Y     29805568
#define OFF_DINV  29805568
#define OFF_W4BT  56151040

// ---------------------------------------------------------------------------
// K0: zero degI (34816 u32). 34 blocks x 256 x int4.
// ---------------------------------------------------------------------------
__global__ __launch_bounds__(256) void k_zero_deg(int4* __restrict__ degI4) {
  degI4[blockIdx.x * 256 + threadIdx.x] = make_int4(0, 0, 0, 0);
}

// ---------------------------------------------------------------------------
// K1: parallel degree. 1024 blocks = 8 per graph, 1024 edges each.
// LDS fixed-point partials (scale 2^20, native ds_add_u32) -> one global
// u32 atomic per touched node.
// ---------------------------------------------------------------------------
__global__ __launch_bounds__(256) void k_deg(
    const int* __restrict__ ei1, const float* __restrict__ ea1,
    const int* __restrict__ ei2, const float* __restrict__ ea2,
    unsigned* __restrict__ degI) {
  int b = blockIdx.x;
  int g = b >> 3, chunk = b & 7;
  const int* ei = (g < 64) ? (ei1 + (size_t)g * 2 * NE) : (ei2 + (size_t)(g - 64) * 2 * NE);
  const float* ea = (g < 64) ? (ea1 + (size_t)g * NE) : (ea2 + (size_t)(g - 64) * NE);
  __shared__ unsigned degL[NN];
  int t = threadIdx.x;
  for (int n = t; n < NN; n += 256) degL[n] = 0u;
  __syncthreads();
  int e0 = chunk * 1024;
#pragma unroll 4
  for (int e = e0 + t; e < e0 + 1024; e += 256) {
    int s = ei[e], d = ei[NE + e];
    float w = ea[e];
    if (s != d) atomicAdd(&degL[s], (unsigned)lrintf(w * 1048576.f));
  }
  __syncthreads();
  for (int n = t; n < NN; n += 256) {
    unsigned v = degL[n];
    if (v) atomicAdd(&degI[(size_t)g * 272 + n], v);
  }
}

// ---------------------------------------------------------------------------
// K2: merged weight conversion + dinv (one launch, 502 blocks x 256 = 128512).
// idx <  55296: W1 [3][268][64] f32 -> WbT [192][288] bf16
// idx <  87552: Wc1 [268][100] f32 -> Wc1bT [112][288] bf16
// idx < 122368: dinv[i] = degI[i]>0 ? rsqrt(degI*2^-20) : 0
// else (6144):  W4 [3][64][32] f32 -> W4bT [96][64] bf16 (n-major)
// ---------------------------------------------------------------------------
__global__ __launch_bounds__(256) void k_conv_weights_dinv(
    const float* __restrict__ W1, const float* __restrict__ Wc1,
    const float* __restrict__ W4, const unsigned* __restrict__ degI,
    short* __restrict__ WbT, short* __restrict__ Wc1bT,
    short* __restrict__ W4bT, float* __restrict__ dinv) {
  int idx = blockIdx.x * 256 + threadIdx.x;
  if (idx < 192 * KP) {
    int n = idx / KP, kp = idx - n * KP;
    int kb = n >> 6, j = n & 63;
    float v = (kp < 268) ? W1[((size_t)kb * 268 + kp) * 64 + j] : 0.f;
    WbT[idx] = f2bf(v);
  } else if (idx < 192 * KP + 112 * KP) {
    int i2 = idx - 192 * KP;  // 0..32255
    int n = i2 / KP, k = i2 - n * KP;
    float v = (n < 100 && k < 268) ? Wc1[(size_t)k * 100 + n] : 0.f;
    Wc1bT[i2] = f2bf(v);
  } else if (idx < 192 * KP + 112 * KP + 34816) {
    int i3 = idx - (192 * KP + 112 * KP);  // 0..34815
    unsigned dI = degI[i3];
    dinv[i3] = dI ? rsqrtf((float)dI * (1.f / 1048576.f)) : 0.f;
  } else {
    int i4 = idx - (192 * KP + 112 * KP + 34816);  // 0..6143
    int n = i4 >> 6, k = i4 & 63;                  // n in [0,96), k in [0,64)
    W4bT[i4] = f2bf(W4[(((size_t)(n >> 5)) * 64 + k) * 32 + (n & 31)]);
  }
}

// ---------------------------------------------------------------------------
// K3: dense Laplacian tiles. Block = (graph, 17-row tile); each block scans
// its graph's FULL edge list (L2-hot: 16 same-graph blocks share one XCD via
// swizzle) and filters d into its 17 rows.
// Round-12 fix: accumulate in FIXED-POINT int (scale 2^24) via native
// ds_add_u32 — LDS *float* atomicAdd is a CAS retry loop (~10K+ serial
// cycles/block was the round-11 42 µs; same pathology as rounds 2/8).
// Range: |nw| <= ~0.2 on this data, dup-accum <= ~1 -> 128x headroom in i32;
// quantum 2^-24 invisible vs bf16. Zero/emit loops are scalar
// lane-consecutive (conflict-free banks; 2B stores still coalesce).
// ---------------------------------------------------------------------------
__global__ __launch_bounds__(256) void k_tile_build2(
    const int* __restrict__ ei1, const float* __restrict__ ea1,
    const int* __restrict__ ei2, const float* __restrict__ ea2,
    const float* __restrict__ dinv_all, short* __restrict__ Lb) {
  int l = blockIdx.x;              // 2048 = 8 xcd * 16 g * 16 tiles
  int xcd = l & 7, rest = l >> 3;  // rest 0..255
  int g = xcd + 8 * (rest & 15);
  int tile = rest >> 4;            // 0..15
  int r0 = tile * 17;
  const int* ei = (g < 64) ? (ei1 + (size_t)g * 2 * NE) : (ei2 + (size_t)(g - 64) * 2 * NE);
  const float* ea = (g < 64) ? (ea1 + (size_t)g * NE) : (ea2 + (size_t)(g - 64) * NE);
  __shared__ int LrowI[17 * 288];
  __shared__ float dv[272];
  int t = threadIdx.x;
  for (int i = t; i < 17 * 288; i += 256) LrowI[i] = 0;
  for (int i = t; i < 272; i += 256) dv[i] = dinv_all[(size_t)g * 272 + i];
  __syncthreads();
#pragma unroll 4
  for (int e = t; e < NE; e += 256) {
    int d = ei[NE + e];
    int s = ei[e];
    float w = ea[e];
    if (d >= r0 && d < r0 + 17 && s != d) {
      atomicAdd(&LrowI[(d - r0) * 288 + s],
                (int)lrintf(-dv[s] * w * dv[d] * 16777216.f));  // native ds_add
    }
  }
  __syncthreads();
  short* Lbg = Lb + (size_t)g * 272 * KP + (size_t)r0 * KP;
  for (int i = t; i < 17 * 288; i += 256)
    Lbg[i] = f2bf((float)LrowI[i] * (1.f / 16777216.f));
}

// ---------------------------------------------------------------------------
// K4: big GEMM on MFMA.  Y[g] = X[g] @ [W1_0|W1_1|W1_2]  (M=268,K=268,N=192)
// fp32 Y out + transposed bf16 copy of the Y2 block: Y2t[g][f][d] (f=col-128).
// ---------------------------------------------------------------------------
__global__ __launch_bounds__(256) void k_gemm1_mfma(
    const float* __restrict__ x1, const float* __restrict__ x2,
    const short* __restrict__ WbT, float* __restrict__ Y,
    short* __restrict__ Y2t) {
  int g = blockIdx.y;
  int m0 = blockIdx.x * 64;
  const float* A32 = (g < 64) ? (x1 + (size_t)g * NN * 268) : (x2 + (size_t)(g - 64) * NN * 268);
  float* Yg = Y + (size_t)g * NN * 192;
  short* Y2tg = Y2t + (size_t)g * 64 * KP;
  __shared__ __align__(16) short As[64][40];
  __shared__ __align__(16) short Bs[192][40];
  int t = threadIdx.x;
  int w = t >> 6, lane = t & 63;
  int quad = lane >> 4, l16 = lane & 15;
  int mh = w & 1, nh = w >> 1;
  f32x4 acc[2][6];
#pragma unroll
  for (int mi = 0; mi < 2; ++mi)
#pragma unroll
    for (int ni = 0; ni < 6; ++ni) acc[mi][ni] = (f32x4){0.f, 0.f, 0.f, 0.f};

  int sr = t >> 2, sko = (t & 3) * 8;
  for (int k0 = 0; k0 < KP; k0 += 32) {
    {
      int row = m0 + sr;
      int k = k0 + sko;
      float4 va = make_float4(0.f, 0.f, 0.f, 0.f), vb = va;
      if (row < NN && k < 268) va = *(const float4*)(A32 + (size_t)row * 268 + k);
      if (row < NN && k + 4 < 268) vb = *(const float4*)(A32 + (size_t)row * 268 + k + 4);
      short8 s;
      s[0] = f2bf(va.x); s[1] = f2bf(va.y); s[2] = f2bf(va.z); s[3] = f2bf(va.w);
      s[4] = f2bf(vb.x); s[5] = f2bf(vb.y); s[6] = f2bf(vb.z); s[7] = f2bf(vb.w);
      *(short8*)(&As[sr][sko]) = s;
    }
#pragma unroll
    for (int i = 0; i < 3; ++i) {
      int r = sr + i * 64;
      *(short8*)(&Bs[r][sko]) = *(const short8*)(WbT + (size_t)r * KP + k0 + sko);
    }
    __syncthreads();
    short8 af[2], bfr[6];
#pragma unroll
    for (int mi = 0; mi < 2; ++mi)
      af[mi] = *(const short8*)(&As[(mh * 2 + mi) * 16 + l16][quad * 8]);
#pragma unroll
    for (int ni = 0; ni < 6; ++ni)
      bfr[ni] = *(const short8*)(&Bs[(nh * 6 + ni) * 16 + l16][quad * 8]);
#pragma unroll
    for (int mi = 0; mi < 2; ++mi)
#pragma unroll
      for (int ni = 0; ni < 6; ++ni)
        acc[mi][ni] = __builtin_amdgcn_mfma_f32_16x16x32_bf16(af[mi], bfr[ni], acc[mi][ni], 0, 0, 0);
    __syncthreads();
  }
  // C/D: col = lane&15, row = quad*4 + reg
#pragma unroll
  for (int mi = 0; mi < 2; ++mi) {
    int rbase = m0 + (mh * 2 + mi) * 16 + quad * 4;
#pragma unroll
    for (int reg = 0; reg < 4; ++reg) {
      int row = rbase + reg;
      if (row < NN) {
#pragma unroll
        for (int ni = 0; ni < 6; ++ni) {
          int col = (nh * 6 + ni) * 16 + l16;
          Yg[(size_t)row * 192 + col] = acc[mi][ni][reg];
        }
      }
    }
    if (rbase < NN) {  // rbase % 4 == 0, never straddles 268
#pragma unroll
      for (int ni = 0; ni < 6; ++ni) {
        int col = (nh * 6 + ni) * 16 + l16;
        if (col >= 128) {
          short4v p;
#pragma unroll
          for (int reg = 0; reg < 4; ++reg) p[reg] = f2bf(acc[mi][ni][reg]);
          *(short4v*)(Y2tg + (size_t)(col - 128) * KP + rbase) = p;
        }
      }
    }
  }
}

// ---------------------------------------------------------------------------
// K5/K6/K7/K8: dense-L MFMA apply, A = Lb[g] [272][288] bf16 (rows d),
// B = Bt[g] [NCOLS][288] bf16 (pre-transposed, col f major, k = s).
// Block 64 rows x NCOLS cols, 4 waves. XCD swizzle (5 blocks/graph share xcd).
// MODE 0: v = Y[d][O1+f] + 2*acc           -> OutB[g][f][d] bf16   (U-type)
// MODE 2: v = relu(Y[d][O1+f]-Y[d][O2+f]+acc+bias[f]) -> H2Tb bf16 (+d-pad 0)
// MODE 3: H1 = relu(Y[d][O1+f]-Y[d][O2+f]+acc+bias[f]) kept in LDS bf16, then
//         fused second MFMA H1 @ W4bT (M=64,N=96,K=64):
//           cols 0-64  -> Y[d][c]      (Yb0|Yb1 fp32)
//           cols 64-96 -> Y[d][c+96]   (Yb2 fp32) + Yb2t[g][c-64][d] bf16
// ---------------------------------------------------------------------------
template <int NCOLS, int MODE, int O1, int O2>
__global__ __launch_bounds__(256) void k_dgemm(
    const short* __restrict__ Lb, const short* __restrict__ Bt,
    float* __restrict__ Y, const float* __restrict__ bias,
    short* __restrict__ OutB, const short* __restrict__ W4bT,
    short* __restrict__ OutB2) {
  int l = blockIdx.x;              // 640 = 8 xcd * 16 * 5
  int xcd = l & 7, idx = l >> 3;   // idx 0..79
  int g = xcd + 8 * (idx / 5);
  int m0 = (idx % 5) * 64;
  const short* Lbg = Lb + (size_t)g * 272 * KP;
  const short* Btg = Bt + (size_t)g * NCOLS * KP;
  float* Yg = Y + (size_t)g * NN * 192;
  __shared__ __align__(16) short As[64][40];
  __shared__ __align__(16) short Bs[NCOLS][40];
  int t = threadIdx.x;
  int w = t >> 6, lane = t & 63;
  int quad = lane >> 4, l16 = lane & 15;
  constexpr int NT = NCOLS / 32;   // n-tiles per wave (2 or 1)
  int mh = w & 1, nh = w >> 1;
  f32x4 acc[2][NT];
#pragma unroll
  for (int mi = 0; mi < 2; ++mi)
#pragma unroll
    for (int ni = 0; ni < NT; ++ni) acc[mi][ni] = (f32x4){0.f, 0.f, 0.f, 0.f};

  int sr = t >> 2, sko = (t & 3) * 8;
  for (int k0 = 0; k0 < KP; k0 += 32) {
    int arow = m0 + sr;
    short8 av;
    if (arow < 272) av = *(const short8*)(Lbg + (size_t)arow * KP + k0 + sko);
    else av = (short8){0, 0, 0, 0, 0, 0, 0, 0};
    *(short8*)(&As[sr][sko]) = av;
    if (sr < NCOLS)
      *(short8*)(&Bs[sr][sko]) = *(const short8*)(Btg + (size_t)sr * KP + k0 + sko);
    __syncthreads();
    short8 af[2], bfr[NT];
#pragma unroll
    for (int mi = 0; mi < 2; ++mi)
      af[mi] = *(const short8*)(&As[(mh * 2 + mi) * 16 + l16][quad * 8]);
#pragma unroll
    for (int ni = 0; ni < NT; ++ni)
      bfr[ni] = *(const short8*)(&Bs[(nh * NT + ni) * 16 + l16][quad * 8]);
#pragma unroll
    for (int mi = 0; mi < 2; ++mi)
#pragma unroll
      for (int ni = 0; ni < NT; ++ni)
        acc[mi][ni] = __builtin_amdgcn_mfma_f32_16x16x32_bf16(af[mi], bfr[ni], acc[mi][ni], 0, 0, 0);
    __syncthreads();
  }

  if constexpr (MODE != 3) {
#pragma unroll
    for (int mi = 0; mi < 2; ++mi) {
      int dbase = m0 + (mh * 2 + mi) * 16 + quad * 4;
      if (dbase < NN) {  // dbase % 4 == 0, never straddles 268
#pragma unroll
        for (int ni = 0; ni < NT; ++ni) {
          int f = (nh * NT + ni) * 16 + l16;
          f32x4 a = acc[mi][ni];
          if (MODE == 0) {
            short4v p;
#pragma unroll
            for (int reg = 0; reg < 4; ++reg)
              p[reg] = f2bf(Yg[(size_t)(dbase + reg) * 192 + O1 + f] + 2.f * a[reg]);
            *(short4v*)(OutB + (size_t)g * NCOLS * KP + (size_t)f * KP + dbase) = p;
          } else {
            short4v p;
#pragma unroll
            for (int reg = 0; reg < 4; ++reg) {
              int d = dbase + reg;
              float v = Yg[(size_t)d * 192 + O1 + f] - Yg[(size_t)d * 192 + O2 + f] +
                        a[reg] + bias[f];
              p[reg] = f2bf(fmaxf(v, 0.f));
            }
            *(short4v*)(OutB + ((size_t)g * 32 + f) * KP + dbase) = p;
          }
        }
      }
    }
    if (MODE == 2 && m0 == 256) {  // zero d-pad 268..287 of this graph's rows
      for (int i = t; i < 32 * 20; i += 256) {
        int f = i / 20, d = 268 + (i - f * 20);
        OutB[((size_t)g * 32 + f) * KP + d] = 0;
      }
    }
  } else {
    // MODE 3: fused H1 -> LDS bf16 -> MFMA @ W4bT -> Yb
    __shared__ __align__(16) short H1s[64][72];   // [local d][f], pad 72
    __shared__ __align__(16) short W4s[96][72];   // [n][k], k in [0,64)
#pragma unroll
    for (int mi = 0; mi < 2; ++mi) {
      int rbase = (mh * 2 + mi) * 16 + quad * 4;  // local row 0..63
      int dbase = m0 + rbase;
#pragma unroll
      for (int ni = 0; ni < NT; ++ni) {
        int f = (nh * NT + ni) * 16 + l16;
        f32x4 a = acc[mi][ni];
#pragma unroll
        for (int reg = 0; reg < 4; ++reg) {
          int d = dbase + reg;
          float v = 0.f;
          if (d < NN)
            v = fmaxf(Yg[(size_t)d * 192 + O1 + f] - Yg[(size_t)d * 192 + O2 + f] +
                      a[reg] + bias[f], 0.f);
          H1s[rbase + reg][f] = f2bf(v);
        }
      }
    }
    for (int i = t; i < 96 * 8; i += 256) {  // 96 rows x 8 short8 groups
      int r = i >> 3, ko = (i & 7) * 8;
      *(short8*)(&W4s[r][ko]) = *(const short8*)(W4bT + r * 64 + ko);
    }
    __syncthreads();
    f32x4 acc2[2][3];
#pragma unroll
    for (int mi = 0; mi < 2; ++mi)
#pragma unroll
      for (int nj = 0; nj < 3; ++nj) acc2[mi][nj] = (f32x4){0.f, 0.f, 0.f, 0.f};
#pragma unroll
    for (int kc = 0; kc < 2; ++kc) {
      short8 a2f[2], b2f[3];
#pragma unroll
      for (int mi = 0; mi < 2; ++mi)
        a2f[mi] = *(const short8*)(&H1s[(mh * 2 + mi) * 16 + l16][kc * 32 + quad * 8]);
#pragma unroll
      for (int nj = 0; nj < 3; ++nj)
        b2f[nj] = *(const short8*)(&W4s[(nh * 3 + nj) * 16 + l16][kc * 32 + quad * 8]);
#pragma unroll
      for (int mi = 0; mi < 2; ++mi)
#pragma unroll
        for (int nj = 0; nj < 3; ++nj)
          acc2[mi][nj] = __builtin_amdgcn_mfma_f32_16x16x32_bf16(a2f[mi], b2f[nj], acc2[mi][nj], 0, 0, 0);
    }
#pragma unroll
    for (int mi = 0; mi < 2; ++mi) {
      int dbase = m0 + (mh * 2 + mi) * 16 + quad * 4;
      if (dbase < NN) {  // dbase % 4 == 0, never straddles 268
#pragma unroll
        for (int nj = 0; nj < 3; ++nj) {
          int c = (nh * 3 + nj) * 16 + l16;  // 0..95
          f32x4 a = acc2[mi][nj];
          int dst = (c < 64) ? c : c + 96;
#pragma unroll
          for (int reg = 0; reg < 4; ++reg)
            Yg[(size_t)(dbase + reg) * 192 + dst] = a[reg];
          if (c >= 64) {
            short4v p;
#pragma unroll
            for (int reg = 0; reg < 4; ++reg) p[reg] = f2bf(a[reg]);
            *(short4v*)(OutB2 + ((size_t)g * 32 + (c - 64)) * KP + dbase) = p;
          }
        }
      }
    }
  }
}

// ---------------------------------------------------------------------------
// K9: fused classifier. Per block: 64 rows of H2Tb [4096][288] bf16.
// L1: MFMA 64x112 (K=288) -> Z1=relu(.+bc1) in LDS (fp32).
// L2: Z2=relu(Z1@Wc2+bc2) register-tiled 2x8 from LDS (fp32).
// L3: out = Z2 . Wc3 + bc3.  Rows (g*32+c) match d_out order.
// ---------------------------------------------------------------------------
__global__ __launch_bounds__(256) void k_cls(
    const short* __restrict__ H2Tb, const short* __restrict__ Wc1bT,
    const float* __restrict__ bc1, const float* __restrict__ Wc2,
    const float* __restrict__ bc2, const float* __restrict__ Wc3,
    const float* __restrict__ bc3, float* __restrict__ out) {
  int m0 = blockIdx.x * 64;
  __shared__ __align__(16) short As[64][40];
  __shared__ __align__(16) short Bs[112][40];
  __shared__ __align__(16) float Z1s[64][116];
  __shared__ __align__(16) float W2s[100][64];
  __shared__ __align__(16) float Z2s[64][64];
  __shared__ float w3s[64];
  int t = threadIdx.x;
  int w = t >> 6, lane = t & 63;
  int quad = lane >> 4, l16 = lane & 15;
  f32x4 acc[7];
#pragma unroll
  for (int ni = 0; ni < 7; ++ni) acc[ni] = (f32x4){0.f, 0.f, 0.f, 0.f};

  int sr = t >> 2, sko = (t & 3) * 8;
  for (int k0 = 0; k0 < KP; k0 += 32) {
    *(short8*)(&As[sr][sko]) = *(const short8*)(H2Tb + (size_t)(m0 + sr) * KP + k0 + sko);
#pragma unroll
    for (int i = 0; i < 2; ++i) {
      int idx = t + i * 256;
      if (idx < 112 * 4) {
        int r = idx >> 2, ko = (idx & 3) * 8;
        *(short8*)(&Bs[r][ko]) = *(const short8*)(Wc1bT + (size_t)r * KP + k0 + ko);
      }
    }
    __syncthreads();
    short8 af = *(const short8*)(&As[w * 16 + l16][quad * 8]);
#pragma unroll
    for (int ni = 0; ni < 7; ++ni) {
      short8 bfr = *(const short8*)(&Bs[ni * 16 + l16][quad * 8]);
      acc[ni] = __builtin_amdgcn_mfma_f32_16x16x32_bf16(af, bfr, acc[ni], 0, 0, 0);
    }
    __syncthreads();
  }
#pragma unroll
  for (int ni = 0; ni < 7; ++ni) {
    int col = ni * 16 + l16;
    if (col < 100) {
      float b = bc1[col];
#pragma unroll
      for (int reg = 0; reg < 4; ++reg) {
        int wrow = w * 16 + quad * 4 + reg;
        Z1s[wrow][col] = fmaxf(acc[ni][reg] + b, 0.f);
      }
    }
  }
  for (int i = t; i < 100 * 64; i += 256) {
    int r = i >> 6, c = i & 63;
    W2s[r][c] = (c < 60) ? Wc2[(size_t)r * 60 + c] : 0.f;
  }
  if (t < 64) w3s[t] = (t < 60) ? Wc3[t] : 0.f;
  __syncthreads();
  {
    int r2 = (t >> 3) * 2;
    int c8 = (t & 7) * 8;
    float a2[2][8];
#pragma unroll
    for (int i = 0; i < 2; ++i)
#pragma unroll
      for (int j = 0; j < 8; ++j) a2[i][j] = 0.f;
#pragma unroll 4
    for (int k = 0; k < 100; ++k) {
      float x0 = Z1s[r2][k], x1 = Z1s[r2 + 1][k];
      float4 wA = *(const float4*)(&W2s[k][c8]);
      float4 wB = *(const float4*)(&W2s[k][c8 + 4]);
      float wv[8] = {wA.x, wA.y, wA.z, wA.w, wB.x, wB.y, wB.z, wB.w};
#pragma unroll
      for (int j = 0; j < 8; ++j) { a2[0][j] += x0 * wv[j]; a2[1][j] += x1 * wv[j]; }
    }
#pragma unroll
    for (int j = 0; j < 8; ++j) {
      int c = c8 + j;
      float bb = (c < 60) ? bc2[c] : 0.f;
      Z2s[r2][c] = fmaxf(a2[0][j] + bb, 0.f);
      Z2s[r2 + 1][c] = fmaxf(a2[1][j] + bb, 0.f);
    }
  }
  __syncthreads();
  if (t < 64) {
    float acc3 = bc3[0];
#pragma unroll
    for (int k = 0; k < 60; ++k) acc3 += Z2s[t][k] * w3s[k];
    out[m0 + t] = acc3;
  }
}

extern "C" void kernel_launch(void* const* d_in, const int* in_sizes, int n_in,
                              void* d_out, int out_size, void* d_ws, size_t ws_size,
                              hipStream_t stream) {
  (void)in_sizes; (void)n_in; (void)out_size; (void)ws_size;
  const float* x1  = (const float*)d_in[0];
  const int*   ei1 = (const int*)d_in[1];
  const float* ea1 = (const float*)d_in[2];
  const float* x2  = (const float*)d_in[3];
  const int*   ei2 = (const int*)d_in[4];
  const float* ea2 = (const float*)d_in[5];
  const float* W1  = (const float*)d_in[6];
  const float* b1  = (const float*)d_in[7];
  const float* W4  = (const float*)d_in[8];
  const float* b4  = (const float*)d_in[9];
  const float* Wc1 = (const float*)d_in[10];
  const float* bc1 = (const float*)d_in[11];
  const float* Wc2 = (const float*)d_in[12];
  const float* bc2 = (const float*)d_in[13];
  const float* Wc3 = (const float*)d_in[14];
  const float* bc3 = (const float*)d_in[15];

  char* ws = (char*)d_ws;
  unsigned* degI = (unsigned*)(ws + OFF_DEGI);
  short* Y2t   = (short*)(ws + OFF_Y2T);
  short* Yb2t  = (short*)(ws + OFF_YB2T);
  short* U2t   = (short*)(ws + OFF_U2T);
  short* Ut    = (short*)(ws + OFF_UT);
  short* H2Tb  = (short*)(ws + OFF_H2TB);
  short* WbT   = (short*)(ws + OFF_WBT);
  short* Wc1bT = (short*)(ws + OFF_WC1BT);
  short* Lb    = (short*)(ws + OFF_LB);
  float* Y     = (float*)(ws + OFF_Y);
  float* dinv  = (float*)(ws + OFF_DINV);
  short* W4bT  = (short*)(ws + OFF_W4BT);
  float* out   = (float*)d_out;

  // parallel edge prep: zero deg, 8-blocks/graph degree, dinv+conv merged
  k_zero_deg<<<34, 256, 0, stream>>>((int4*)degI);
  k_deg<<<1024, 256, 0, stream>>>(ei1, ea1, ei2, ea2, degI);
  k_conv_weights_dinv<<<502, 256, 0, stream>>>(W1, Wc1, W4, degI, WbT, Wc1bT, W4bT, dinv);
  // dense bf16 Laplacian, fixed-point LDS accumulation (native ds_add)
  k_tile_build2<<<2048, 256, 0, stream>>>(ei1, ea1, ei2, ea2, dinv, Lb);
  // Y = X @ [W1_0|W1_1|W1_2] via MFMA; side-output Y2t (bf16, transposed)
  k_gemm1_mfma<<<dim3(5, 128), 256, 0, stream>>>(x1, x2, WbT, Y, Y2t);
  // cheb1: Ut = bf16(Y1 + 2*L@Y2)
  k_dgemm<64, 0, 64, 0><<<640, 256, 0, stream>>>(Lb, Y2t, Y, nullptr, Ut, nullptr, nullptr);
  // cheb1 finish + cheb2 input FUSED: H1=relu(Y0-Y2+L@Ut+b1) (LDS only),
  // then Yb = H1 @ W4 -> Y cols {0-64,160-192} + Yb2t bf16
  k_dgemm<64, 3, 0, 128><<<640, 256, 0, stream>>>(Lb, Ut, Y, b1, nullptr, W4bT, Yb2t);
  // cheb2: U2t = bf16(Yb1 + 2*L@Yb2); H2Tb = relu(Yb0 - Yb2 + L@U2 + b4)
  k_dgemm<32, 0, 32, 0><<<640, 256, 0, stream>>>(Lb, Yb2t, Y, nullptr, U2t, nullptr, nullptr);
  k_dgemm<32, 2, 0, 160><<<640, 256, 0, stream>>>(Lb, U2t, Y, b4, H2Tb, nullptr, nullptr);
  // fused classifier
  k_cls<<<64, 256, 0, stream>>>(H2Tb, Wc1bT, bc1, Wc2, bc2, Wc3, bc3, out);
}

// Round 13
// 230.579 us; speedup vs baseline: 1.0471x; 1.0471x over previous
//
#include <hip/hip_runtime.h>
#include <hip/hip_bf16.h>

#define NN 268
#define NE 8192
#define KP 288   // padded K (268 -> 288), shared by gemm1 / dense L / classifier

typedef short short8 __attribute__((ext_vector_type(8)));   // 8 bf16 = 4 VGPR
typedef short short4v __attribute__((ext_vector_type(4)));  // 4 bf16 = 8B
typedef float f32x4 __attribute__((ext_vector_type(4)));

__device__ __forceinline__ short f2bf(float f) {
  __hip_bfloat16 h = __float2bfloat16(f);
  return *reinterpret_cast<short*>(&h);
}

// ---------------------------------------------------------------------------
// Workspace offsets (bytes). Peak 56,163,328.
//   OFF_DEGI   degI   u32 [128][272]             139,264  (dead after dinv calc)
//   OFF_Y2T    Y2t    bf16[128][64][288]       4,718,592  (dead after dgemmA)
//     OFF_YB2T Yb2t   bf16[128][32][288]       2,359,296  (overlays Y2t head)
//     OFF_U2T  U2t    bf16[128][32][288]       2,359,296  (overlays Y2t tail)
//   OFF_UT     Ut     bf16[128][64][288]       4,718,592  (dead after dgemmB)
//     OFF_H2TB H2Tb   bf16[4096][288]          2,359,296  (overlays Ut head)
//   OFF_WBT    WbT    bf16[192][288]             110,592
//   OFF_WC1BT  Wc1bT  bf16[112][288]              64,512
//   OFF_LB     Lb     bf16[128][272][288]     20,054,016
//   OFF_Y      Y      f32 [128][268][192]     26,345,472
//   OFF_W4BT   W4bT   bf16[96][64]                12,288
//     dinv f32[128][272] (139 KB) overlays Y head — dead before gemm1 writes Y
//     Y cols per graph: 0-64 Y0 (later Yb0|Yb1), 64-128 Y1 (dead after dgemmA),
//                       128-192 Y2 (later cols 160-192 = Yb2)
// ---------------------------------------------------------------------------
#define OFF_DEGI  0
#define OFF_Y2T   139264
#define OFF_YB2T  139264
#define OFF_U2T   2498560
#define OFF_UT    4857856
#define OFF_H2TB  4857856
#define OFF_WBT   9576448
#define OFF_WC1BT 9687040
#define OFF_LB    9751552
#define OFF_Y     29805568
#define OFF_DINV  29805568
#define OFF_W4BT  56151040

// ---------------------------------------------------------------------------
// K0: zero degI (34816 u32). 34 blocks x 256 x int4.
// ---------------------------------------------------------------------------
__global__ __launch_bounds__(256) void k_zero_deg(int4* __restrict__ degI4) {
  degI4[blockIdx.x * 256 + threadIdx.x] = make_int4(0, 0, 0, 0);
}

// ---------------------------------------------------------------------------
// K1: parallel degree. 1024 blocks = 8 per graph, 1024 edges each.
// LDS fixed-point partials (scale 2^20, native ds_add_u32) -> one global
// u32 atomic per touched node.
// ---------------------------------------------------------------------------
__global__ __launch_bounds__(256) void k_deg(
    const int* __restrict__ ei1, const float* __restrict__ ea1,
    const int* __restrict__ ei2, const float* __restrict__ ea2,
    unsigned* __restrict__ degI) {
  int b = blockIdx.x;
  int g = b >> 3, chunk = b & 7;
  const int* ei = (g < 64) ? (ei1 + (size_t)g * 2 * NE) : (ei2 + (size_t)(g - 64) * 2 * NE);
  const float* ea = (g < 64) ? (ea1 + (size_t)g * NE) : (ea2 + (size_t)(g - 64) * NE);
  __shared__ unsigned degL[NN];
  int t = threadIdx.x;
  for (int n = t; n < NN; n += 256) degL[n] = 0u;
  __syncthreads();
  int e0 = chunk * 1024;
#pragma unroll 4
  for (int e = e0 + t; e < e0 + 1024; e += 256) {
    int s = ei[e], d = ei[NE + e];
    float w = ea[e];
    if (s != d) atomicAdd(&degL[s], (unsigned)lrintf(w * 1048576.f));
  }
  __syncthreads();
  for (int n = t; n < NN; n += 256) {
    unsigned v = degL[n];
    if (v) atomicAdd(&degI[(size_t)g * 272 + n], v);
  }
}

// ---------------------------------------------------------------------------
// K2: merged weight conversion + dinv (one launch, 502 blocks x 256 = 128512).
// idx <  55296: W1 [3][268][64] f32 -> WbT [192][288] bf16
// idx <  87552: Wc1 [268][100] f32 -> Wc1bT [112][288] bf16
// idx < 122368: dinv[i] = degI[i]>0 ? rsqrt(degI*2^-20) : 0
// else (6144):  W4 [3][64][32] f32 -> W4bT [96][64] bf16 (n-major)
// ---------------------------------------------------------------------------
__global__ __launch_bounds__(256) void k_conv_weights_dinv(
    const float* __restrict__ W1, const float* __restrict__ Wc1,
    const float* __restrict__ W4, const unsigned* __restrict__ degI,
    short* __restrict__ WbT, short* __restrict__ Wc1bT,
    short* __restrict__ W4bT, float* __restrict__ dinv) {
  int idx = blockIdx.x * 256 + threadIdx.x;
  if (idx < 192 * KP) {
    int n = idx / KP, kp = idx - n * KP;
    int kb = n >> 6, j = n & 63;
    float v = (kp < 268) ? W1[((size_t)kb * 268 + kp) * 64 + j] : 0.f;
    WbT[idx] = f2bf(v);
  } else if (idx < 192 * KP + 112 * KP) {
    int i2 = idx - 192 * KP;  // 0..32255
    int n = i2 / KP, k = i2 - n * KP;
    float v = (n < 100 && k < 268) ? Wc1[(size_t)k * 100 + n] : 0.f;
    Wc1bT[i2] = f2bf(v);
  } else if (idx < 192 * KP + 112 * KP + 34816) {
    int i3 = idx - (192 * KP + 112 * KP);  // 0..34815
    unsigned dI = degI[i3];
    dinv[i3] = dI ? rsqrtf((float)dI * (1.f / 1048576.f)) : 0.f;
  } else {
    int i4 = idx - (192 * KP + 112 * KP + 34816);  // 0..6143
    int n = i4 >> 6, k = i4 & 63;                  // n in [0,96), k in [0,64)
    W4bT[i4] = f2bf(W4[(((size_t)(n >> 5)) * 64 + k) * 32 + (n & 31)]);
  }
}

// ---------------------------------------------------------------------------
// K3: dense Laplacian tiles. Round-13: 34-row tiles (was 17) -> 1024 blocks
// = 4 blocks/CU, ALL resident in one round (no sequential generations), and
// total redundant edge-visits halve (8.4M vs 16.8M). LDS 34x288 int + dv =
// 40.3 KB -> exactly 4 blocks/CU of the 160 KB pool. unroll 8 -> 24 loads in
// flight across 16 waves/CU. Fixed-point int accumulation (scale 2^24,
// native ds_add) kept from round 12 (it removed the bank conflicts).
// ---------------------------------------------------------------------------
__global__ __launch_bounds__(256) void k_tile_build2(
    const int* __restrict__ ei1, const float* __restrict__ ea1,
    const int* __restrict__ ei2, const float* __restrict__ ea2,
    const float* __restrict__ dinv_all, short* __restrict__ Lb) {
  int l = blockIdx.x;              // 1024 = 8 xcd * 16 g * 8 tiles
  int xcd = l & 7, rest = l >> 3;  // rest 0..127
  int g = xcd + 8 * (rest & 15);
  int tile = rest >> 4;            // 0..7
  int r0 = tile * 34;
  const int* ei = (g < 64) ? (ei1 + (size_t)g * 2 * NE) : (ei2 + (size_t)(g - 64) * 2 * NE);
  const float* ea = (g < 64) ? (ea1 + (size_t)g * NE) : (ea2 + (size_t)(g - 64) * NE);
  __shared__ int LrowI[34 * 288];
  __shared__ float dv[272];
  int t = threadIdx.x;
  for (int i = t; i < 34 * 288; i += 256) LrowI[i] = 0;
  for (int i = t; i < 272; i += 256) dv[i] = dinv_all[(size_t)g * 272 + i];
  __syncthreads();
#pragma unroll 8
  for (int e = t; e < NE; e += 256) {
    int d = ei[NE + e];
    int s = ei[e];
    float w = ea[e];
    if (d >= r0 && d < r0 + 34 && s != d) {
      atomicAdd(&LrowI[(d - r0) * 288 + s],
                (int)lrintf(-dv[s] * w * dv[d] * 16777216.f));  // native ds_add
    }
  }
  __syncthreads();
  short* Lbg = Lb + (size_t)g * 272 * KP + (size_t)r0 * KP;
  for (int i = t; i < 34 * 288; i += 256)
    Lbg[i] = f2bf((float)LrowI[i] * (1.f / 16777216.f));
}

// ---------------------------------------------------------------------------
// K4: big GEMM on MFMA.  Y[g] = X[g] @ [W1_0|W1_1|W1_2]  (M=268,K=268,N=192)
// fp32 Y out + transposed bf16 copy of the Y2 block: Y2t[g][f][d] (f=col-128).
// ---------------------------------------------------------------------------
__global__ __launch_bounds__(256) void k_gemm1_mfma(
    const float* __restrict__ x1, const float* __restrict__ x2,
    const short* __restrict__ WbT, float* __restrict__ Y,
    short* __restrict__ Y2t) {
  int g = blockIdx.y;
  int m0 = blockIdx.x * 64;
  const float* A32 = (g < 64) ? (x1 + (size_t)g * NN * 268) : (x2 + (size_t)(g - 64) * NN * 268);
  float* Yg = Y + (size_t)g * NN * 192;
  short* Y2tg = Y2t + (size_t)g * 64 * KP;
  __shared__ __align__(16) short As[64][40];
  __shared__ __align__(16) short Bs[192][40];
  int t = threadIdx.x;
  int w = t >> 6, lane = t & 63;
  int quad = lane >> 4, l16 = lane & 15;
  int mh = w & 1, nh = w >> 1;
  f32x4 acc[2][6];
#pragma unroll
  for (int mi = 0; mi < 2; ++mi)
#pragma unroll
    for (int ni = 0; ni < 6; ++ni) acc[mi][ni] = (f32x4){0.f, 0.f, 0.f, 0.f};

  int sr = t >> 2, sko = (t & 3) * 8;
  for (int k0 = 0; k0 < KP; k0 += 32) {
    {
      int row = m0 + sr;
      int k = k0 + sko;
      float4 va = make_float4(0.f, 0.f, 0.f, 0.f), vb = va;
      if (row < NN && k < 268) va = *(const float4*)(A32 + (size_t)row * 268 + k);
      if (row < NN && k + 4 < 268) vb = *(const float4*)(A32 + (size_t)row * 268 + k + 4);
      short8 s;
      s[0] = f2bf(va.x); s[1] = f2bf(va.y); s[2] = f2bf(va.z); s[3] = f2bf(va.w);
      s[4] = f2bf(vb.x); s[5] = f2bf(vb.y); s[6] = f2bf(vb.z); s[7] = f2bf(vb.w);
      *(short8*)(&As[sr][sko]) = s;
    }
#pragma unroll
    for (int i = 0; i < 3; ++i) {
      int r = sr + i * 64;
      *(short8*)(&Bs[r][sko]) = *(const short8*)(WbT + (size_t)r * KP + k0 + sko);
    }
    __syncthreads();
    short8 af[2], bfr[6];
#pragma unroll
    for (int mi = 0; mi < 2; ++mi)
      af[mi] = *(const short8*)(&As[(mh * 2 + mi) * 16 + l16][quad * 8]);
#pragma unroll
    for (int ni = 0; ni < 6; ++ni)
      bfr[ni] = *(const short8*)(&Bs[(nh * 6 + ni) * 16 + l16][quad * 8]);
#pragma unroll
    for (int mi = 0; mi < 2; ++mi)
#pragma unroll
      for (int ni = 0; ni < 6; ++ni)
        acc[mi][ni] = __builtin_amdgcn_mfma_f32_16x16x32_bf16(af[mi], bfr[ni], acc[mi][ni], 0, 0, 0);
    __syncthreads();
  }
  // C/D: col = lane&15, row = quad*4 + reg
#pragma unroll
  for (int mi = 0; mi < 2; ++mi) {
    int rbase = m0 + (mh * 2 + mi) * 16 + quad * 4;
#pragma unroll
    for (int reg = 0; reg < 4; ++reg) {
      int row = rbase + reg;
      if (row < NN) {
#pragma unroll
        for (int ni = 0; ni < 6; ++ni) {
          int col = (nh * 6 + ni) * 16 + l16;
          Yg[(size_t)row * 192 + col] = acc[mi][ni][reg];
        }
      }
    }
    if (rbase < NN) {  // rbase % 4 == 0, never straddles 268
#pragma unroll
      for (int ni = 0; ni < 6; ++ni) {
        int col = (nh * 6 + ni) * 16 + l16;
        if (col >= 128) {
          short4v p;
#pragma unroll
          for (int reg = 0; reg < 4; ++reg) p[reg] = f2bf(acc[mi][ni][reg]);
          *(short4v*)(Y2tg + (size_t)(col - 128) * KP + rbase) = p;
        }
      }
    }
  }
}

// ---------------------------------------------------------------------------
// K5/K6/K7/K8: dense-L MFMA apply, A = Lb[g] [272][288] bf16 (rows d),
// B = Bt[g] [NCOLS][288] bf16 (pre-transposed, col f major, k = s).
// Block 64 rows x NCOLS cols, 4 waves. XCD swizzle (5 blocks/graph share xcd).
// MODE 0: v = Y[d][O1+f] + 2*acc           -> OutB[g][f][d] bf16   (U-type)
// MODE 2: v = relu(Y[d][O1+f]-Y[d][O2+f]+acc+bias[f]) -> H2Tb bf16 (+d-pad 0)
// MODE 3: H1 = relu(Y[d][O1+f]-Y[d][O2+f]+acc+bias[f]) kept in LDS bf16, then
//         fused second MFMA H1 @ W4bT (M=64,N=96,K=64):
//           cols 0-64  -> Y[d][c]      (Yb0|Yb1 fp32)
//           cols 64-96 -> Y[d][c+96]   (Yb2 fp32) + Yb2t[g][c-64][d] bf16
// ---------------------------------------------------------------------------
template <int NCOLS, int MODE, int O1, int O2>
__global__ __launch_bounds__(256) void k_dgemm(
    const short* __restrict__ Lb, const short* __restrict__ Bt,
    float* __restrict__ Y, const float* __restrict__ bias,
    short* __restrict__ OutB, const short* __restrict__ W4bT,
    short* __restrict__ OutB2) {
  int l = blockIdx.x;              // 640 = 8 xcd * 16 * 5
  int xcd = l & 7, idx = l >> 3;   // idx 0..79
  int g = xcd + 8 * (idx / 5);
  int m0 = (idx % 5) * 64;
  const short* Lbg = Lb + (size_t)g * 272 * KP;
  const short* Btg = Bt + (size_t)g * NCOLS * KP;
  float* Yg = Y + (size_t)g * NN * 192;
  __shared__ __align__(16) short As[64][40];
  __shared__ __align__(16) short Bs[NCOLS][40];
  int t = threadIdx.x;
  int w = t >> 6, lane = t & 63;
  int quad = lane >> 4, l16 = lane & 15;
  constexpr int NT = NCOLS / 32;   // n-tiles per wave (2 or 1)
  int mh = w & 1, nh = w >> 1;
  f32x4 acc[2][NT];
#pragma unroll
  for (int mi = 0; mi < 2; ++mi)
#pragma unroll
    for (int ni = 0; ni < NT; ++ni) acc[mi][ni] = (f32x4){0.f, 0.f, 0.f, 0.f};

  int sr = t >> 2, sko = (t & 3) * 8;
  for (int k0 = 0; k0 < KP; k0 += 32) {
    int arow = m0 + sr;
    short8 av;
    if (arow < 272) av = *(const short8*)(Lbg + (size_t)arow * KP + k0 + sko);
    else av = (short8){0, 0, 0, 0, 0, 0, 0, 0};
    *(short8*)(&As[sr][sko]) = av;
    if (sr < NCOLS)
      *(short8*)(&Bs[sr][sko]) = *(const short8*)(Btg + (size_t)sr * KP + k0 + sko);
    __syncthreads();
    short8 af[2], bfr[NT];
#pragma unroll
    for (int mi = 0; mi < 2; ++mi)
      af[mi] = *(const short8*)(&As[(mh * 2 + mi) * 16 + l16][quad * 8]);
#pragma unroll
    for (int ni = 0; ni < NT; ++ni)
      bfr[ni] = *(const short8*)(&Bs[(nh * NT + ni) * 16 + l16][quad * 8]);
#pragma unroll
    for (int mi = 0; mi < 2; ++mi)
#pragma unroll
      for (int ni = 0; ni < NT; ++ni)
        acc[mi][ni] = __builtin_amdgcn_mfma_f32_16x16x32_bf16(af[mi], bfr[ni], acc[mi][ni], 0, 0, 0);
    __syncthreads();
  }

  if constexpr (MODE != 3) {
#pragma unroll
    for (int mi = 0; mi < 2; ++mi) {
      int dbase = m0 + (mh * 2 + mi) * 16 + quad * 4;
      if (dbase < NN) {  // dbase % 4 == 0, never straddles 268
#pragma unroll
        for (int ni = 0; ni < NT; ++ni) {
          int f = (nh * NT + ni) * 16 + l16;
          f32x4 a = acc[mi][ni];
          if (MODE == 0) {
            short4v p;
#pragma unroll
            for (int reg = 0; reg < 4; ++reg)
              p[reg] = f2bf(Yg[(size_t)(dbase + reg) * 192 + O1 + f] + 2.f * a[reg]);
            *(short4v*)(OutB + (size_t)g * NCOLS * KP + (size_t)f * KP + dbase) = p;
          } else {
            short4v p;
#pragma unroll
            for (int reg = 0; reg < 4; ++reg) {
              int d = dbase + reg;
              float v = Yg[(size_t)d * 192 + O1 + f] - Yg[(size_t)d * 192 + O2 + f] +
                        a[reg] + bias[f];
              p[reg] = f2bf(fmaxf(v, 0.f));
            }
            *(short4v*)(OutB + ((size_t)g * 32 + f) * KP + dbase) = p;
          }
        }
      }
    }
    if (MODE == 2 && m0 == 256) {  // zero d-pad 268..287 of this graph's rows
      for (int i = t; i < 32 * 20; i += 256) {
        int f = i / 20, d = 268 + (i - f * 20);
        OutB[((size_t)g * 32 + f) * KP + d] = 0;
      }
    }
  } else {
    // MODE 3: fused H1 -> LDS bf16 -> MFMA @ W4bT -> Yb
    __shared__ __align__(16) short H1s[64][72];   // [local d][f], pad 72
    __shared__ __align__(16) short W4s[96][72];   // [n][k], k in [0,64)
#pragma unroll
    for (int mi = 0; mi < 2; ++mi) {
      int rbase = (mh * 2 + mi) * 16 + quad * 4;  // local row 0..63
      int dbase = m0 + rbase;
#pragma unroll
      for (int ni = 0; ni < NT; ++ni) {
        int f = (nh * NT + ni) * 16 + l16;
        f32x4 a = acc[mi][ni];
#pragma unroll
        for (int reg = 0; reg < 4; ++reg) {
          int d = dbase + reg;
          float v = 0.f;
          if (d < NN)
            v = fmaxf(Yg[(size_t)d * 192 + O1 + f] - Yg[(size_t)d * 192 + O2 + f] +
                      a[reg] + bias[f], 0.f);
          H1s[rbase + reg][f] = f2bf(v);
        }
      }
    }
    for (int i = t; i < 96 * 8; i += 256) {  // 96 rows x 8 short8 groups
      int r = i >> 3, ko = (i & 7) * 8;
      *(short8*)(&W4s[r][ko]) = *(const short8*)(W4bT + r * 64 + ko);
    }
    __syncthreads();
    f32x4 acc2[2][3];
#pragma unroll
    for (int mi = 0; mi < 2; ++mi)
#pragma unroll
      for (int nj = 0; nj < 3; ++nj) acc2[mi][nj] = (f32x4){0.f, 0.f, 0.f, 0.f};
#pragma unroll
    for (int kc = 0; kc < 2; ++kc) {
      short8 a2f[2], b2f[3];
#pragma unroll
      for (int mi = 0; mi < 2; ++mi)
        a2f[mi] = *(const short8*)(&H1s[(mh * 2 + mi) * 16 + l16][kc * 32 + quad * 8]);
#pragma unroll
      for (int nj = 0; nj < 3; ++nj)
        b2f[nj] = *(const short8*)(&W4s[(nh * 3 + nj) * 16 + l16][kc * 32 + quad * 8]);
#pragma unroll
      for (int mi = 0; mi < 2; ++mi)
#pragma unroll
        for (int nj = 0; nj < 3; ++nj)
          acc2[mi][nj] = __builtin_amdgcn_mfma_f32_16x16x32_bf16(a2f[mi], b2f[nj], acc2[mi][nj], 0, 0, 0);
    }
#pragma unroll
    for (int mi = 0; mi < 2; ++mi) {
      int dbase = m0 + (mh * 2 + mi) * 16 + quad * 4;
      if (dbase < NN) {  // dbase % 4 == 0, never straddles 268
#pragma unroll
        for (int nj = 0; nj < 3; ++nj) {
          int c = (nh * 3 + nj) * 16 + l16;  // 0..95
          f32x4 a = acc2[mi][nj];
          int dst = (c < 64) ? c : c + 96;
#pragma unroll
          for (int reg = 0; reg < 4; ++reg)
            Yg[(size_t)(dbase + reg) * 192 + dst] = a[reg];
          if (c >= 64) {
            short4v p;
#pragma unroll
            for (int reg = 0; reg < 4; ++reg) p[reg] = f2bf(a[reg]);
            *(short4v*)(OutB2 + ((size_t)g * 32 + (c - 64)) * KP + dbase) = p;
          }
        }
      }
    }
  }
}

// ---------------------------------------------------------------------------
// K9: fused classifier. Per block: 64 rows of H2Tb [4096][288] bf16.
// L1: MFMA 64x112 (K=288) -> Z1=relu(.+bc1) in LDS (fp32).
// L2: Z2=relu(Z1@Wc2+bc2) register-tiled 2x8 from LDS (fp32).
// L3: out = Z2 . Wc3 + bc3.  Rows (g*32+c) match d_out order.
// ---------------------------------------------------------------------------
__global__ __launch_bounds__(256) void k_cls(
    const short* __restrict__ H2Tb, const short* __restrict__ Wc1bT,
    const float* __restrict__ bc1, const float* __restrict__ Wc2,
    const float* __restrict__ bc2, const float* __restrict__ Wc3,
    const float* __restrict__ bc3, float* __restrict__ out) {
  int m0 = blockIdx.x * 64;
  __shared__ __align__(16) short As[64][40];
  __shared__ __align__(16) short Bs[112][40];
  __shared__ __align__(16) float Z1s[64][116];
  __shared__ __align__(16) float W2s[100][64];
  __shared__ __align__(16) float Z2s[64][64];
  __shared__ float w3s[64];
  int t = threadIdx.x;
  int w = t >> 6, lane = t & 63;
  int quad = lane >> 4, l16 = lane & 15;
  f32x4 acc[7];
#pragma unroll
  for (int ni = 0; ni < 7; ++ni) acc[ni] = (f32x4){0.f, 0.f, 0.f, 0.f};

  int sr = t >> 2, sko = (t & 3) * 8;
  for (int k0 = 0; k0 < KP; k0 += 32) {
    *(short8*)(&As[sr][sko]) = *(const short8*)(H2Tb + (size_t)(m0 + sr) * KP + k0 + sko);
#pragma unroll
    for (int i = 0; i < 2; ++i) {
      int idx = t + i * 256;
      if (idx < 112 * 4) {
        int r = idx >> 2, ko = (idx & 3) * 8;
        *(short8*)(&Bs[r][ko]) = *(const short8*)(Wc1bT + (size_t)r * KP + k0 + ko);
      }
    }
    __syncthreads();
    short8 af = *(const short8*)(&As[w * 16 + l16][quad * 8]);
#pragma unroll
    for (int ni = 0; ni < 7; ++ni) {
      short8 bfr = *(const short8*)(&Bs[ni * 16 + l16][quad * 8]);
      acc[ni] = __builtin_amdgcn_mfma_f32_16x16x32_bf16(af, bfr, acc[ni], 0, 0, 0);
    }
    __syncthreads();
  }
#pragma unroll
  for (int ni = 0; ni < 7; ++ni) {
    int col = ni * 16 + l16;
    if (col < 100) {
      float b = bc1[col];
#pragma unroll
      for (int reg = 0; reg < 4; ++reg) {
        int wrow = w * 16 + quad * 4 + reg;
        Z1s[wrow][col] = fmaxf(acc[ni][reg] + b, 0.f);
      }
    }
  }
  for (int i = t; i < 100 * 64; i += 256) {
    int r = i >> 6, c = i & 63;
    W2s[r][c] = (c < 60) ? Wc2[(size_t)r * 60 + c] : 0.f;
  }
  if (t < 64) w3s[t] = (t < 60) ? Wc3[t] : 0.f;
  __syncthreads();
  {
    int r2 = (t >> 3) * 2;
    int c8 = (t & 7) * 8;
    float a2[2][8];
#pragma unroll
    for (int i = 0; i < 2; ++i)
#pragma unroll
      for (int j = 0; j < 8; ++j) a2[i][j] = 0.f;
#pragma unroll 4
    for (int k = 0; k < 100; ++k) {
      float x0 = Z1s[r2][k], x1 = Z1s[r2 + 1][k];
      float4 wA = *(const float4*)(&W2s[k][c8]);
      float4 wB = *(const float4*)(&W2s[k][c8 + 4]);
      float wv[8] = {wA.x, wA.y, wA.z, wA.w, wB.x, wB.y, wB.z, wB.w};
#pragma unroll
      for (int j = 0; j < 8; ++j) { a2[0][j] += x0 * wv[j]; a2[1][j] += x1 * wv[j]; }
    }
#pragma unroll
    for (int j = 0; j < 8; ++j) {
      int c = c8 + j;
      float bb = (c < 60) ? bc2[c] : 0.f;
      Z2s[r2][c] = fmaxf(a2[0][j] + bb, 0.f);
      Z2s[r2 + 1][c] = fmaxf(a2[1][j] + bb, 0.f);
    }
  }
  __syncthreads();
  if (t < 64) {
    float acc3 = bc3[0];
#pragma unroll
    for (int k = 0; k < 60; ++k) acc3 += Z2s[t][k] * w3s[k];
    out[m0 + t] = acc3;
  }
}

extern "C" void kernel_launch(void* const* d_in, const int* in_sizes, int n_in,
                              void* d_out, int out_size, void* d_ws, size_t ws_size,
                              hipStream_t stream) {
  (void)in_sizes; (void)n_in; (void)out_size; (void)ws_size;
  const float* x1  = (const float*)d_in[0];
  const int*   ei1 = (const int*)d_in[1];
  const float* ea1 = (const float*)d_in[2];
  const float* x2  = (const float*)d_in[3];
  const int*   ei2 = (const int*)d_in[4];
  const float* ea2 = (const float*)d_in[5];
  const float* W1  = (const float*)d_in[6];
  const float* b1  = (const float*)d_in[7];
  const float* W4  = (const float*)d_in[8];
  const float* b4  = (const float*)d_in[9];
  const float* Wc1 = (const float*)d_in[10];
  const float* bc1 = (const float*)d_in[11];
  const float* Wc2 = (const float*)d_in[12];
  const float* bc2 = (const float*)d_in[13];
  const float* Wc3 = (const float*)d_in[14];
  const float* bc3 = (const float*)d_in[15];

  char* ws = (char*)d_ws;
  unsigned* degI = (unsigned*)(ws + OFF_DEGI);
  short* Y2t   = (short*)(ws + OFF_Y2T);
  short* Yb2t  = (short*)(ws + OFF_YB2T);
  short* U2t   = (short*)(ws + OFF_U2T);
  short* Ut    = (short*)(ws + OFF_UT);
  short* H2Tb  = (short*)(ws + OFF_H2TB);
  short* WbT   = (short*)(ws + OFF_WBT);
  short* Wc1bT = (short*)(ws + OFF_WC1BT);
  short* Lb    = (short*)(ws + OFF_LB);
  float* Y     = (float*)(ws + OFF_Y);
  float* dinv  = (float*)(ws + OFF_DINV);
  short* W4bT  = (short*)(ws + OFF_W4BT);
  float* out   = (float*)d_out;

  // parallel edge prep: zero deg, 8-blocks/graph degree, dinv+conv merged
  k_zero_deg<<<34, 256, 0, stream>>>((int4*)degI);
  k_deg<<<1024, 256, 0, stream>>>(ei1, ea1, ei2, ea2, degI);
  k_conv_weights_dinv<<<502, 256, 0, stream>>>(W1, Wc1, W4, degI, WbT, Wc1bT, W4bT, dinv);
  // dense bf16 Laplacian, 34-row tiles: 1024 blocks all co-resident (4/CU)
  k_tile_build2<<<1024, 256, 0, stream>>>(ei1, ea1, ei2, ea2, dinv, Lb);
  // Y = X @ [W1_0|W1_1|W1_2] via MFMA; side-output Y2t (bf16, transposed)
  k_gemm1_mfma<<<dim3(5, 128), 256, 0, stream>>>(x1, x2, WbT, Y, Y2t);
  // cheb1: Ut = bf16(Y1 + 2*L@Y2)
  k_dgemm<64, 0, 64, 0><<<640, 256, 0, stream>>>(Lb, Y2t, Y, nullptr, Ut, nullptr, nullptr);
  // cheb1 finish + cheb2 input FUSED: H1=relu(Y0-Y2+L@Ut+b1) (LDS only),
  // then Yb = H1 @ W4 -> Y cols {0-64,160-192} + Yb2t bf16
  k_dgemm<64, 3, 0, 128><<<640, 256, 0, stream>>>(Lb, Ut, Y, b1, nullptr, W4bT, Yb2t);
  // cheb2: U2t = bf16(Yb1 + 2*L@Yb2); H2Tb = relu(Yb0 - Yb2 + L@U2 + b4)
  k_dgemm<32, 0, 32, 0><<<640, 256, 0, stream>>>(Lb, Yb2t, Y, nullptr, U2t, nullptr, nullptr);
  k_dgemm<32, 2, 0, 160><<<640, 256, 0, stream>>>(Lb, U2t, Y, b4, H2Tb, nullptr, nullptr);
  // fused classifier
  k_cls<<<64, 256, 0, stream>>>(H2Tb, Wc1bT, bc1, Wc2, bc2, Wc3, bc3, out);
}